// Round 1
// baseline (228.412 us; speedup 1.0000x reference)
//
#include <hip/hip_runtime.h>

typedef __attribute__((ext_vector_type(8))) short bf16x8;
typedef __attribute__((ext_vector_type(4))) float f32x4;

#define NQ   4096
#define NKV  4096
#define CDIM 256
#define HEADS 8
#define DDIM 32

// f32 -> bf16 RNE
__device__ __forceinline__ unsigned short f2bf(float x){
  unsigned int u = __builtin_bit_cast(unsigned int, x);
  u = (u + 0x7FFFu + ((u >> 16) & 1u)) >> 16;
  return (unsigned short)u;
}

__device__ __forceinline__ void cvt8(const float* __restrict__ in,
                                     unsigned short* __restrict__ out, int i){
  const float4* p = (const float4*)in;
  float4 a = p[2*i], b = p[2*i+1];
  union { unsigned short u[8]; bf16x8 v; } o;
  o.u[0]=f2bf(a.x); o.u[1]=f2bf(a.y); o.u[2]=f2bf(a.z); o.u[3]=f2bf(a.w);
  o.u[4]=f2bf(b.x); o.u[5]=f2bf(b.y); o.u[6]=f2bf(b.z); o.u[7]=f2bf(b.w);
  ((bf16x8*)out)[i] = o.v;
}

// One launch: convert query/key_value to bf16 (same layout) and the three
// weight matrices to bf16 TRANSPOSED [N][K] so GEMM B-fragments are contiguous.
__global__ __launch_bounds__(256) void prep(
    const float* __restrict__ q, const float* __restrict__ kv,
    const float* __restrict__ wq, const float* __restrict__ wkv,
    const float* __restrict__ wout,
    unsigned short* __restrict__ qx, unsigned short* __restrict__ kvx,
    unsigned short* __restrict__ wqT, unsigned short* __restrict__ wkvT,
    unsigned short* __restrict__ woutT)
{
  int t = blockIdx.x * 256 + threadIdx.x;
  if (t < 262144){ cvt8(q, qx, t); }
  else if (t < 524288){ cvt8(kv, kvx, t - 262144); }
  else {
    int i = t - 524288;                       // 0 .. 262143
    if (i < 65536){ int n = i >> 8, k = i & 255; wqT[i] = f2bf(wq[k*256 + n]); }
    else if (i < 196608){ int j = i - 65536; int n = j >> 8, k = j & 255;
                          wkvT[j] = f2bf(wkv[k*512 + n]); }
    else { int j = i - 196608; int n = j >> 8, k = j & 255;
           woutT[j] = f2bf(wout[k*256 + n]); }
  }
}

// GEMM: X[M][256] bf16 @ WT[N][256]^T.  Block = 64x64 tile, 4 waves (each 64x16).
// MODE 0: -> Q [b][h][q][32] bf16, scaled by D^-0.5 * log2(e)
// MODE 1: -> K [b][h][kv][32] bf16 (cols 0..255), V^T [b][h][32][kv] (cols 256..511)
// MODE 2: -> f32 out [m][256] + bias
template<int MODE>
__global__ __launch_bounds__(256) void gemm_proj(
    const unsigned short* __restrict__ X,
    const unsigned short* __restrict__ WT,
    unsigned short* __restrict__ O1,
    unsigned short* __restrict__ O2,
    float* __restrict__ FO,
    const float* __restrict__ bias)
{
  const int wid = threadIdx.x >> 6;
  const int lane = threadIdx.x & 63;
  const int l15 = lane & 15, g = lane >> 4;
  const int m0 = blockIdx.x * 64;
  const int n0 = blockIdx.y * 64 + wid * 16;
  f32x4 acc[4] = {{0,0,0,0},{0,0,0,0},{0,0,0,0},{0,0,0,0}};
  const unsigned short* xp = X + (size_t)(m0 + l15) * CDIM + g * 8;
  const unsigned short* wp = WT + (size_t)(n0 + l15) * CDIM + g * 8;
  #pragma unroll
  for (int k0 = 0; k0 < CDIM; k0 += 32){
    bf16x8 bfr = *(const bf16x8*)(wp + k0);
    #pragma unroll
    for (int i = 0; i < 4; ++i){
      bf16x8 afr = *(const bf16x8*)(xp + (size_t)i*16*CDIM + k0);
      acc[i] = __builtin_amdgcn_mfma_f32_16x16x32_bf16(afr, bfr, acc[i], 0, 0, 0);
    }
  }
  #pragma unroll
  for (int i = 0; i < 4; ++i){
    #pragma unroll
    for (int r = 0; r < 4; ++r){
      int m = m0 + i*16 + g*4 + r;            // row = (lane>>4)*4 + reg (verified C/D layout)
      int n = n0 + l15;                       // col = lane&15
      float v = acc[i][r];
      int b = m >> 12, pos = m & 4095;
      if (MODE == 0){
        int h = n >> 5, d = n & 31;
        O1[((size_t)(b*HEADS + h)*NQ + pos)*DDIM + d] = f2bf(v * 0.25503227f);
      } else if (MODE == 1){
        if (n < 256){
          int h = n >> 5, d = n & 31;
          O1[((size_t)(b*HEADS + h)*NKV + pos)*DDIM + d] = f2bf(v);
        } else {
          int c = n - 256, h = c >> 5, d = c & 31;
          O2[((size_t)(b*HEADS + h)*DDIM + d)*NKV + pos] = f2bf(v);
        }
      } else {
        FO[(size_t)m*CDIM + n] = v + bias[n];
      }
    }
  }
}

// Flash attention. 4 waves/block, 16 q-rows/wave, KVBLK=32, D=32=K of one MFMA.
// Swapped QK^T: S^T = mfma(Kfrag, Qfrag) -> lane holds 8 scores for q = lane&15.
__global__ __launch_bounds__(256) void attn_kernel(
    const unsigned short* __restrict__ Qb,
    const unsigned short* __restrict__ Kb,
    const unsigned short* __restrict__ VT,
    unsigned short* __restrict__ AO)
{
  __shared__ unsigned short plds[4][16][40];   // per-wave P^T staging, pad 40 (16B-aligned rows)
  const int wid = threadIdx.x >> 6;
  const int lane = threadIdx.x & 63;
  const int l15 = lane & 15, g = lane >> 4;
  const int bh = blockIdx.y;                    // b*8 + h
  const int q0 = blockIdx.x * 64 + wid * 16;
  const unsigned short* Qp = Qb + ((size_t)bh*NQ + q0)*DDIM;
  const unsigned short* Kp = Kb + (size_t)bh*NKV*DDIM;
  const unsigned short* Vp = VT + (size_t)bh*DDIM*NKV;
  bf16x8 qf = *(const bf16x8*)(Qp + l15*DDIM + g*8);   // Q[q0+l15][8g..8g+7] (scale folded)
  f32x4 acc0 = {0,0,0,0}, acc1 = {0,0,0,0};            // out[q=4g+r][d=l15], [d=16+l15]
  float mrun = -1e30f, lrun = 0.0f;
  const f32x4 zero = {0,0,0,0};
  for (int kv0 = 0; kv0 < NKV; kv0 += 32){
    bf16x8 kf0 = *(const bf16x8*)(Kp + (size_t)(kv0 + l15)*DDIM + g*8);
    bf16x8 kf1 = *(const bf16x8*)(Kp + (size_t)(kv0 + 16 + l15)*DDIM + g*8);
    bf16x8 vf0 = *(const bf16x8*)(Vp + (size_t)l15*NKV + kv0 + g*8);
    bf16x8 vf1 = *(const bf16x8*)(Vp + (size_t)(16 + l15)*NKV + kv0 + g*8);
    // S^T tiles: lane l reg r = S[q=l15][kv = kv0 + 16t + 4g + r]  (exp2 domain)
    f32x4 s0 = __builtin_amdgcn_mfma_f32_16x16x32_bf16(kf0, qf, zero, 0, 0, 0);
    f32x4 s1 = __builtin_amdgcn_mfma_f32_16x16x32_bf16(kf1, qf, zero, 0, 0, 0);
    float pm = fmaxf(fmaxf(fmaxf(s0[0], s0[1]), fmaxf(s0[2], s0[3])),
                     fmaxf(fmaxf(s1[0], s1[1]), fmaxf(s1[2], s1[3])));
    pm = fmaxf(pm, __shfl_xor(pm, 16));
    pm = fmaxf(pm, __shfl_xor(pm, 32));
    float mnew = fmaxf(mrun, pm);
    float alpha = __builtin_amdgcn_exp2f(mrun - mnew);
    float p[8];
    float ps = 0.0f;
    #pragma unroll
    for (int r = 0; r < 4; ++r){ p[r]   = __builtin_amdgcn_exp2f(s0[r] - mnew); ps += p[r]; }
    #pragma unroll
    for (int r = 0; r < 4; ++r){ p[4+r] = __builtin_amdgcn_exp2f(s1[r] - mnew); ps += p[4+r]; }
    ps += __shfl_xor(ps, 16);
    ps += __shfl_xor(ps, 32);
    lrun = lrun * alpha + ps;
    mrun = mnew;
    // rescale accumulator rows (acc row q' = 4g+r; alpha lives at lane q')
    #pragma unroll
    for (int r = 0; r < 4; ++r){
      float ar = __shfl(alpha, g*4 + r);
      acc0[r] *= ar; acc1[r] *= ar;
    }
    // P (bf16) -> LDS transposed to PV A-fragment layout
    unsigned int pk0, pk1, pk2, pk3;
    asm("v_cvt_pk_bf16_f32 %0, %1, %2" : "=v"(pk0) : "v"(p[0]), "v"(p[1]));
    asm("v_cvt_pk_bf16_f32 %0, %1, %2" : "=v"(pk1) : "v"(p[2]), "v"(p[3]));
    asm("v_cvt_pk_bf16_f32 %0, %1, %2" : "=v"(pk2) : "v"(p[4]), "v"(p[5]));
    asm("v_cvt_pk_bf16_f32 %0, %1, %2" : "=v"(pk3) : "v"(p[6]), "v"(p[7]));
    unsigned int* pw = (unsigned int*)(&plds[wid][l15][0]);
    pw[g*2]         = pk0;     // kv-local 4g..4g+1
    pw[g*2 + 1]     = pk1;     // kv-local 4g+2..4g+3
    pw[8 + g*2]     = pk2;     // kv-local 16+4g..16+4g+1
    pw[8 + g*2 + 1] = pk3;
    asm volatile("s_waitcnt lgkmcnt(0)" ::: "memory");  // wave-internal cross-lane LDS dep
    bf16x8 pa = *(const bf16x8*)(&plds[wid][l15][g*8]); // P[q=l15][kv=8g..8g+7]
    acc0 = __builtin_amdgcn_mfma_f32_16x16x32_bf16(pa, vf0, acc0, 0, 0, 0);
    acc1 = __builtin_amdgcn_mfma_f32_16x16x32_bf16(pa, vf1, acc1, 0, 0, 0);
  }
  float linv = 1.0f / lrun;
  int b = bh >> 3, h = bh & 7;
  #pragma unroll
  for (int r = 0; r < 4; ++r){
    float li = __shfl(linv, g*4 + r);
    int q = q0 + g*4 + r;
    size_t base = ((size_t)b*NQ + q)*CDIM + h*DDIM;
    AO[base + l15]      = f2bf(acc0[r] * li);
    AO[base + 16 + l15] = f2bf(acc1[r] * li);
  }
}

extern "C" void kernel_launch(void* const* d_in, const int* in_sizes, int n_in,
                              void* d_out, int out_size, void* d_ws, size_t ws_size,
                              hipStream_t stream)
{
  const float* query     = (const float*)d_in[0];
  const float* key_value = (const float*)d_in[1];
  const float* w_q       = (const float*)d_in[2];
  const float* w_kv      = (const float*)d_in[3];
  const float* w_out     = (const float*)d_in[4];
  const float* b_out     = (const float*)d_in[5];
  float* out = (float*)d_out;
  char* ws = (char*)d_ws;
  // workspace layout (bytes); AO aliases qx (qx dead after proj_q). ~21.5 MB total.
  unsigned short* qx    = (unsigned short*)(ws + 0);         // 8192*256 bf16
  unsigned short* kvx   = (unsigned short*)(ws + 4194304);   // 8192*256 bf16
  unsigned short* wqT   = (unsigned short*)(ws + 8388608);   // 256*256
  unsigned short* wkvT  = (unsigned short*)(ws + 8519680);   // 512*256
  unsigned short* woutT = (unsigned short*)(ws + 8781824);   // 256*256
  unsigned short* Qb    = (unsigned short*)(ws + 8912896);   // [2][8][4096][32]
  unsigned short* Kb    = (unsigned short*)(ws + 13107200);  // [2][8][4096][32]
  unsigned short* VTb   = (unsigned short*)(ws + 17301504);  // [2][8][32][4096]
  unsigned short* AO    = qx;                                // [8192][256] bf16

  prep<<<3072, 256, 0, stream>>>(query, key_value, w_q, w_kv, w_out,
                                 qx, kvx, wqT, wkvT, woutT);
  gemm_proj<0><<<dim3(128, 4), 256, 0, stream>>>(qx,  wqT,   Qb, nullptr, nullptr, nullptr);
  gemm_proj<1><<<dim3(128, 8), 256, 0, stream>>>(kvx, wkvT,  Kb, VTb,     nullptr, nullptr);
  attn_kernel<<<dim3(64, 16), 256, 0, stream>>>(Qb, Kb, VTb, AO);
  gemm_proj<2><<<dim3(128, 4), 256, 0, stream>>>(AO,  woutT, nullptr, nullptr, out, b_out);
}

// Round 2
// 144.347 us; speedup vs baseline: 1.5824x; 1.5824x over previous
//
#include <hip/hip_runtime.h>

typedef __attribute__((ext_vector_type(8))) short bf16x8;
typedef __attribute__((ext_vector_type(4))) float f32x4;
typedef __attribute__((ext_vector_type(16))) float f32x16;

#define NQ   4096
#define NKV  4096
#define CDIM 256
#define HEADS 8
#define DDIM 32

// f32 -> bf16 RNE
__device__ __forceinline__ unsigned short f2bf(float x){
  unsigned int u = __builtin_bit_cast(unsigned int, x);
  u = (u + 0x7FFFu + ((u >> 16) & 1u)) >> 16;
  return (unsigned short)u;
}

__device__ __forceinline__ void cvt8(const float* __restrict__ in,
                                     unsigned short* __restrict__ out, int i){
  const float4* p = (const float4*)in;
  float4 a = p[2*i], b = p[2*i+1];
  union { unsigned short u[8]; bf16x8 v; } o;
  o.u[0]=f2bf(a.x); o.u[1]=f2bf(a.y); o.u[2]=f2bf(a.z); o.u[3]=f2bf(a.w);
  o.u[4]=f2bf(b.x); o.u[5]=f2bf(b.y); o.u[6]=f2bf(b.z); o.u[7]=f2bf(b.w);
  ((bf16x8*)out)[i] = o.v;
}

// Convert activations to bf16 (same layout) and weights to bf16 transposed [N][K].
__global__ __launch_bounds__(256) void prep(
    const float* __restrict__ q, const float* __restrict__ kv,
    const float* __restrict__ wq, const float* __restrict__ wkv,
    const float* __restrict__ wout,
    unsigned short* __restrict__ qx, unsigned short* __restrict__ kvx,
    unsigned short* __restrict__ wqT, unsigned short* __restrict__ wkvT,
    unsigned short* __restrict__ woutT)
{
  int t = blockIdx.x * 256 + threadIdx.x;
  if (t < 262144){ cvt8(q, qx, t); }
  else if (t < 524288){ cvt8(kv, kvx, t - 262144); }
  else {
    int i = t - 524288;                       // 0 .. 262143
    if (i < 65536){ int n = i >> 8, k = i & 255; wqT[i] = f2bf(wq[k*256 + n]); }
    else if (i < 196608){ int j = i - 65536; int n = j >> 8, k = j & 255;
                          wkvT[j] = f2bf(wkv[k*512 + n]); }
    else { int j = i - 196608; int n = j >> 8, k = j & 255;
           woutT[j] = f2bf(wout[k*256 + n]); }
  }
}

// Fused Q + KV projection. blockIdx.y < 4 -> Q-mode (N=256); else KV-mode (N=512).
// Block = 64x64 tile, 4 waves (each 64x16). 16x16x32 MFMA, K=256.
__global__ __launch_bounds__(256) void gemm_qkv(
    const unsigned short* __restrict__ qx,
    const unsigned short* __restrict__ kvx,
    const unsigned short* __restrict__ wqT,
    const unsigned short* __restrict__ wkvT,
    unsigned short* __restrict__ Qb,
    unsigned short* __restrict__ Kb,
    unsigned short* __restrict__ VTb)
{
  const int wid = threadIdx.x >> 6;
  const int lane = threadIdx.x & 63;
  const int l15 = lane & 15, g = lane >> 4;
  const int m0 = blockIdx.x * 64;
  const int mode = blockIdx.y >= 4;
  const int ny = mode ? (blockIdx.y - 4) : blockIdx.y;
  const int n0 = ny * 64 + wid * 16;
  const unsigned short* X  = mode ? kvx  : qx;
  const unsigned short* WT = mode ? wkvT : wqT;
  f32x4 acc[4] = {{0,0,0,0},{0,0,0,0},{0,0,0,0},{0,0,0,0}};
  const unsigned short* xp = X + (size_t)(m0 + l15) * CDIM + g * 8;
  const unsigned short* wp = WT + (size_t)(n0 + l15) * CDIM + g * 8;
  #pragma unroll
  for (int k0 = 0; k0 < CDIM; k0 += 32){
    bf16x8 bfr = *(const bf16x8*)(wp + k0);
    #pragma unroll
    for (int i = 0; i < 4; ++i){
      bf16x8 afr = *(const bf16x8*)(xp + (size_t)i*16*CDIM + k0);
      acc[i] = __builtin_amdgcn_mfma_f32_16x16x32_bf16(afr, bfr, acc[i], 0, 0, 0);
    }
  }
  #pragma unroll
  for (int i = 0; i < 4; ++i){
    #pragma unroll
    for (int r = 0; r < 4; ++r){
      int m = m0 + i*16 + g*4 + r;
      int n = n0 + l15;
      float v = acc[i][r];
      int b = m >> 12, pos = m & 4095;
      if (!mode){
        int h = n >> 5, d = n & 31;
        // scale = D^-0.5 * log2(e) folded into Q
        Qb[((size_t)(b*HEADS + h)*NQ + pos)*DDIM + d] = f2bf(v * 0.25503227f);
      } else if (n < 256){
        int h = n >> 5, d = n & 31;
        Kb[((size_t)(b*HEADS + h)*NKV + pos)*DDIM + d] = f2bf(v);
      } else {
        int c = n - 256, h = c >> 5, d = c & 31;
        VTb[((size_t)(b*HEADS + h)*DDIM + d)*NKV + pos] = f2bf(v);
      }
    }
  }
}

// Out projection: AO[M][256] bf16 @ woutT -> f32 + bias.
__global__ __launch_bounds__(256) void gemm_out(
    const unsigned short* __restrict__ X,
    const unsigned short* __restrict__ WT,
    float* __restrict__ FO,
    const float* __restrict__ bias)
{
  const int wid = threadIdx.x >> 6;
  const int lane = threadIdx.x & 63;
  const int l15 = lane & 15, g = lane >> 4;
  const int m0 = blockIdx.x * 64;
  const int n0 = blockIdx.y * 64 + wid * 16;
  f32x4 acc[4] = {{0,0,0,0},{0,0,0,0},{0,0,0,0},{0,0,0,0}};
  const unsigned short* xp = X + (size_t)(m0 + l15) * CDIM + g * 8;
  const unsigned short* wp = WT + (size_t)(n0 + l15) * CDIM + g * 8;
  #pragma unroll
  for (int k0 = 0; k0 < CDIM; k0 += 32){
    bf16x8 bfr = *(const bf16x8*)(wp + k0);
    #pragma unroll
    for (int i = 0; i < 4; ++i){
      bf16x8 afr = *(const bf16x8*)(xp + (size_t)i*16*CDIM + k0);
      acc[i] = __builtin_amdgcn_mfma_f32_16x16x32_bf16(afr, bfr, acc[i], 0, 0, 0);
    }
  }
  #pragma unroll
  for (int i = 0; i < 4; ++i){
    #pragma unroll
    for (int r = 0; r < 4; ++r){
      int m = m0 + i*16 + g*4 + r;
      int n = n0 + l15;
      FO[(size_t)m*CDIM + n] = acc[i][r] + bias[n];
    }
  }
}

// Flash attention v2: 32x32x16 MFMA, QBLK=32/wave, KVBLK=32, kv-split 2.
// Swapped QK^T (S^T: col=q lane-local softmax), O^T accumulation (alpha, 1/l lane-local).
// P-transpose fully in-register: 8 cvt_pk + 4 permlane32_swap. Zero LDS in main loop.
// Defer-max THR=8 (exp2 domain), bias -m folded into MFMA C operand.
__global__ __launch_bounds__(256, 4) void attn2(
    const unsigned short* __restrict__ Qb,
    const unsigned short* __restrict__ Kb,
    const unsigned short* __restrict__ VT,
    unsigned short* __restrict__ AO)
{
  __shared__ float mrg[2][18][64];   // [qtile-in-block][16 acc regs + m + l][lane]
  const int wid = threadIdx.x >> 6;
  const int lane = threadIdx.x & 63;
  const int l31 = lane & 31, g1 = lane >> 5;
  // bijective XCD swizzle: all 64 blocks of a bh land on one XCD (2 bh/XCD -> 1MB L2 set)
  const int lin = blockIdx.x;
  const int xcd = lin & 7;
  const int t = lin >> 3;
  const int qpair = t & 63;
  const int bh = xcd + 8 * (t >> 6);
  const int qtile = qpair * 2 + (wid >> 1);
  const int kvhalf = wid & 1;
  const int q0 = qtile * 32;

  const unsigned short* Qp = Qb + ((size_t)bh * NQ + q0) * DDIM;
  const unsigned short* Kp = Kb + ((size_t)bh * NKV + kvhalf * 2048) * DDIM;
  const unsigned short* Vp = VT + ((size_t)bh * DDIM + l31) * NKV + kvhalf * 2048;

  // Q B-fragments (B[k=d][col=q=l31]): lane needs Q[q=l31][d=16s+8g1+j]
  const bf16x8 qf0 = *(const bf16x8*)(Qp + l31 * DDIM + 8 * g1);
  const bf16x8 qf1 = *(const bf16x8*)(Qp + l31 * DDIM + 16 + 8 * g1);

  f32x16 acc, csplat;
  #pragma unroll
  for (int j = 0; j < 16; ++j){ acc[j] = 0.0f; csplat[j] = 0.0f; }
  float mrun = 0.0f, lrun = 0.0f;

  for (int it = 0; it < 64; ++it){
    const unsigned short* kp = Kp + (size_t)(it * 32 + l31) * DDIM + 8 * g1;
    bf16x8 kf0 = *(const bf16x8*)(kp);        // A: K[kv=l31][d=8g1..], step0
    bf16x8 kf1 = *(const bf16x8*)(kp + 16);   // step1 (d=16+8g1..)
    const unsigned short* vp = Vp + it * 32 + 8 * g1;
    bf16x8 vf0 = *(const bf16x8*)(vp);        // A: V^T[d=l31][kv=8g1..], step0
    bf16x8 vf1 = *(const bf16x8*)(vp + 16);   // step1

    // S^T = K·Q^T - m  (C = -m splat; col=q=l31, row-pattern=kv)
    __builtin_amdgcn_s_setprio(1);
    f32x16 s = __builtin_amdgcn_mfma_f32_32x32x16_bf16(kf0, qf0, csplat, 0, 0, 0);
    s = __builtin_amdgcn_mfma_f32_32x32x16_bf16(kf1, qf1, s, 0, 0, 0);
    __builtin_amdgcn_s_setprio(0);

    // per-lane max over 16 biased scores (max3-friendly groups)
    float pmax = fmaxf(
        fmaxf(fmaxf(fmaxf(s[0], s[1]), s[2]), fmaxf(fmaxf(s[3], s[4]), s[5])),
        fmaxf(fmaxf(fmaxf(s[6], s[7]), s[8]), fmaxf(fmaxf(fmaxf(s[9], s[10]), s[11]),
              fmaxf(fmaxf(fmaxf(s[12], s[13]), s[14]), s[15]))));
    if (!__all(pmax <= 8.0f)){
      // rare rescale path: per-q-row max across the two 32-lane halves
      float aw = pmax, bw = pmax;
      asm("v_permlane32_swap_b32 %0, %1" : "+v"(aw), "+v"(bw));
      float rm = fmaxf(fmaxf(aw, bw), 0.0f);
      float alpha = __builtin_amdgcn_exp2f(-rm);
      #pragma unroll
      for (int j = 0; j < 16; ++j){ s[j] -= rm; acc[j] *= alpha; }
      lrun *= alpha;
      mrun += rm;
      #pragma unroll
      for (int j = 0; j < 16; ++j) csplat[j] = -mrun;
    }
    #pragma unroll
    for (int j = 0; j < 16; ++j) s[j] = __builtin_amdgcn_exp2f(s[j]);
    // row sum
    float ps = ((s[0]+s[1]) + (s[2]+s[3])) + ((s[4]+s[5]) + (s[6]+s[7]))
             + (((s[8]+s[9]) + (s[10]+s[11])) + ((s[12]+s[13]) + (s[14]+s[15])));
    { float aw = ps, bw = ps;
      asm("v_permlane32_swap_b32 %0, %1" : "+v"(aw), "+v"(bw));
      ps = aw + bw; }
    lrun += ps;

    // P -> bf16 PV B-fragments, fully in-register (T12 adapted to 32x32):
    unsigned int u0,u1,u2,u3,u4,u5,u6,u7;
    asm("v_cvt_pk_bf16_f32 %0, %1, %2" : "=v"(u0) : "v"(s[0]),  "v"(s[1]));
    asm("v_cvt_pk_bf16_f32 %0, %1, %2" : "=v"(u1) : "v"(s[2]),  "v"(s[3]));
    asm("v_cvt_pk_bf16_f32 %0, %1, %2" : "=v"(u2) : "v"(s[4]),  "v"(s[5]));
    asm("v_cvt_pk_bf16_f32 %0, %1, %2" : "=v"(u3) : "v"(s[6]),  "v"(s[7]));
    asm("v_cvt_pk_bf16_f32 %0, %1, %2" : "=v"(u4) : "v"(s[8]),  "v"(s[9]));
    asm("v_cvt_pk_bf16_f32 %0, %1, %2" : "=v"(u5) : "v"(s[10]), "v"(s[11]));
    asm("v_cvt_pk_bf16_f32 %0, %1, %2" : "=v"(u6) : "v"(s[12]), "v"(s[13]));
    asm("v_cvt_pk_bf16_f32 %0, %1, %2" : "=v"(u7) : "v"(s[14]), "v"(s[15]));
    asm("v_permlane32_swap_b32 %0, %1" : "+v"(u0), "+v"(u2));
    asm("v_permlane32_swap_b32 %0, %1" : "+v"(u1), "+v"(u3));
    asm("v_permlane32_swap_b32 %0, %1" : "+v"(u4), "+v"(u6));
    asm("v_permlane32_swap_b32 %0, %1" : "+v"(u5), "+v"(u7));
    union { unsigned int u[4]; bf16x8 v; } f0, f1;
    f0.u[0]=u0; f0.u[1]=u1; f0.u[2]=u2; f0.u[3]=u3;
    f1.u[0]=u4; f1.u[1]=u5; f1.u[2]=u6; f1.u[3]=u7;

    // O^T += V^T · P^T   (row-pattern=d, col=q=l31)
    __builtin_amdgcn_s_setprio(1);
    acc = __builtin_amdgcn_mfma_f32_32x32x16_bf16(vf0, f0.v, acc, 0, 0, 0);
    acc = __builtin_amdgcn_mfma_f32_32x32x16_bf16(vf1, f1.v, acc, 0, 0, 0);
    __builtin_amdgcn_s_setprio(0);
  }

  // merge the two kv-halves of each q-tile, then write output (even waves)
  const int pr = wid >> 1;
  if (wid & 1){
    #pragma unroll
    for (int j = 0; j < 16; ++j) mrg[pr][j][lane] = acc[j];
    mrg[pr][16][lane] = mrun;
    mrg[pr][17][lane] = lrun;
  }
  __syncthreads();
  if (!(wid & 1)){
    float m1 = mrg[pr][16][lane], l1 = mrg[pr][17][lane];
    float m = fmaxf(mrun, m1);
    float a0 = __builtin_amdgcn_exp2f(mrun - m);
    float a1 = __builtin_amdgcn_exp2f(m1 - m);
    float linv = 1.0f / (lrun * a0 + l1 * a1);
    a0 *= linv; a1 *= linv;
    int b = bh >> 3, h = bh & 7;
    size_t rowbase = ((size_t)b * NQ + q0 + l31) * CDIM + h * DDIM;
    #pragma unroll
    for (int u = 0; u < 4; ++u){
      float o0 = acc[4*u+0]*a0 + mrg[pr][4*u+0][lane]*a1;
      float o1 = acc[4*u+1]*a0 + mrg[pr][4*u+1][lane]*a1;
      float o2 = acc[4*u+2]*a0 + mrg[pr][4*u+2][lane]*a1;
      float o3 = acc[4*u+3]*a0 + mrg[pr][4*u+3][lane]*a1;
      unsigned int w0, w1;
      asm("v_cvt_pk_bf16_f32 %0, %1, %2" : "=v"(w0) : "v"(o0), "v"(o1));
      asm("v_cvt_pk_bf16_f32 %0, %1, %2" : "=v"(w1) : "v"(o2), "v"(o3));
      unsigned int* dst = (unsigned int*)(AO + rowbase + 8*u + 4*g1);
      dst[0] = w0; dst[1] = w1;
    }
  }
}

extern "C" void kernel_launch(void* const* d_in, const int* in_sizes, int n_in,
                              void* d_out, int out_size, void* d_ws, size_t ws_size,
                              hipStream_t stream)
{
  const float* query     = (const float*)d_in[0];
  const float* key_value = (const float*)d_in[1];
  const float* w_q       = (const float*)d_in[2];
  const float* w_kv      = (const float*)d_in[3];
  const float* w_out     = (const float*)d_in[4];
  const float* b_out     = (const float*)d_in[5];
  float* out = (float*)d_out;
  char* ws = (char*)d_ws;
  unsigned short* qx    = (unsigned short*)(ws + 0);         // 8192*256 bf16
  unsigned short* kvx   = (unsigned short*)(ws + 4194304);   // 8192*256 bf16
  unsigned short* wqT   = (unsigned short*)(ws + 8388608);   // 256*256
  unsigned short* wkvT  = (unsigned short*)(ws + 8519680);   // 512*256
  unsigned short* woutT = (unsigned short*)(ws + 8781824);   // 256*256
  unsigned short* Qb    = (unsigned short*)(ws + 8912896);   // [2][8][4096][32]
  unsigned short* Kb    = (unsigned short*)(ws + 13107200);  // [2][8][4096][32]
  unsigned short* VTb   = (unsigned short*)(ws + 17301504);  // [2][8][32][4096]
  unsigned short* AO    = qx;                                // [8192][256] bf16 (qx dead)

  prep<<<3072, 256, 0, stream>>>(query, key_value, w_q, w_kv, w_out,
                                 qx, kvx, wqT, wkvT, woutT);
  gemm_qkv<<<dim3(128, 12), 256, 0, stream>>>(qx, kvx, wqT, wkvT, Qb, Kb, VTb);
  attn2<<<1024, 256, 0, stream>>>(Qb, Kb, VTb, AO);
  gemm_out<<<dim3(128, 4), 256, 0, stream>>>(AO, woutT, out, b_out);
}